// Round 1
// baseline (19.026 us; speedup 1.0000x reference)
//
#include <hip/hip_runtime.h>

#define BB 4
#define TT 256
#define DD 1024

__global__ __launch_bounds__(256) void sbl_stencil_kernel(
    const float* __restrict__ feat,
    const float* __restrict__ wl, const float* __restrict__ bl,
    const float* __restrict__ wr, const float* __restrict__ br,
    const float* __restrict__ fcw, const float* __restrict__ fcb,
    float* __restrict__ out)
{
    // cw[kh*18 + s]: effective stencil weights, 1/18 mean folded in
    __shared__ float cw[54];
    __shared__ float cconst;

    const int tid = threadIdx.x;
    if (tid < 54) {
        const int kh = tid / 18;
        const int s  = tid % 18;
        const bool left = (s < 9);
        const int j = left ? s : (s - 9);
        const float* W = left ? wl : wr;
        float g0 = 0.f, g1 = 0.f, g2 = 0.f;
        #pragma unroll
        for (int c = 0; c < 5; ++c) {
            const float f = fcw[c];
            g0 += f * W[c * 9 + kh * 3 + 0];
            g1 += f * W[c * 9 + kh * 3 + 1];
            g2 += f * W[c * 9 + kh * 3 + 2];
        }
        // width-sum of same-padded 3-wide conv: edge columns lose one tap
        const float h = (j == 0) ? (g0 + g1)
                      : (j == 8) ? (g1 + g2)
                                 : (g0 + g1 + g2);
        cw[tid] = h * (1.0f / 18.0f);
    } else if (tid == 54) {
        // constant term: (Bl + Br)/2 + fc_b, where Bx = Σ_c fc[c]*conv_x_b[c]
        float c0 = 0.f;
        #pragma unroll
        for (int c = 0; c < 5; ++c) c0 += fcw[c] * (bl[c] + br[c]);
        cconst = 0.5f * c0 + fcb[0];
    }
    __syncthreads();

    const int blk = blockIdx.x;      // b*T + t
    const int b = blk >> 8;          // T = 256
    const int t = blk & 255;
    const int d0 = tid * 4;

    const float C = cconst;
    float acc0 = C, acc1 = C, acc2 = C, acc3 = C;

    const float* fb = feat + (size_t)b * TT * DD;

    #pragma unroll
    for (int s = 0; s < 18; ++s) {
        const int off = (s < 9) ? (s - 10) : (s - 7);
        const int tt = t + off;
        if (tt < 0 || tt >= TT) continue;   // time zero-pad (uniform branch)
        const float* row = fb + (size_t)tt * DD;
        const float4 v = *reinterpret_cast<const float4*>(row + d0);
        const float vm1 = (d0 > 0)       ? row[d0 - 1] : 0.0f;  // d zero-pad
        const float vp4 = (d0 + 4 < DD)  ? row[d0 + 4] : 0.0f;  // d zero-pad
        const float w0 = cw[0 * 18 + s];
        const float w1 = cw[1 * 18 + s];
        const float w2 = cw[2 * 18 + s];
        // out[d0+i] += w0*v[i-1] + w1*v[i] + w2*v[i+1]
        acc0 += w0 * vm1 + w1 * v.x + w2 * v.y;
        acc1 += w0 * v.x + w1 * v.y + w2 * v.z;
        acc2 += w0 * v.y + w1 * v.z + w2 * v.w;
        acc3 += w0 * v.z + w1 * v.w + w2 * vp4;
    }

    float4 o;
    o.x = acc0; o.y = acc1; o.z = acc2; o.w = acc3;
    *reinterpret_cast<float4*>(out + (size_t)blk * DD + d0) = o;
}

extern "C" void kernel_launch(void* const* d_in, const int* in_sizes, int n_in,
                              void* d_out, int out_size, void* d_ws, size_t ws_size,
                              hipStream_t stream) {
    const float* feat = (const float*)d_in[0];
    const float* wl   = (const float*)d_in[1];
    const float* bl   = (const float*)d_in[2];
    const float* wr   = (const float*)d_in[3];
    const float* br   = (const float*)d_in[4];
    const float* fcw  = (const float*)d_in[5];
    const float* fcb  = (const float*)d_in[6];
    float* out = (float*)d_out;

    dim3 grid(BB * TT);   // 1024 blocks, one per (b,t)
    dim3 block(256);      // 4 d's per thread
    sbl_stencil_kernel<<<grid, block, 0, stream>>>(feat, wl, bl, wr, br, fcw, fcb, out);
}

// Round 2
// 13.615 us; speedup vs baseline: 1.3974x; 1.3974x over previous
//
#include <hip/hip_runtime.h>

#define BB 4
#define TT 256
#define DD 1024

__global__ __launch_bounds__(256) void sbl_stencil2_kernel(
    const float* __restrict__ feat,
    const float* __restrict__ wl, const float* __restrict__ bl,
    const float* __restrict__ wr, const float* __restrict__ br,
    const float* __restrict__ fcw, const float* __restrict__ fcb,
    float* __restrict__ out)
{
    // cw[kh*18 + s]: effective stencil weights, 1/18 mean folded in.
    // kh=0 multiplies f[d-1], kh=1 f[d], kh=2 f[d+1] in out[d].
    __shared__ float cw[54];
    __shared__ float cconst;
    __shared__ float edgeA[4], edgeE[4];

    const int tid = threadIdx.x;
    if (tid < 54) {
        const int kh = tid / 18;
        const int s  = tid % 18;
        const bool left = (s < 9);
        const int j = left ? s : (s - 9);
        const float* W = left ? wl : wr;
        float g0 = 0.f, g1 = 0.f, g2 = 0.f;
        #pragma unroll
        for (int c = 0; c < 5; ++c) {
            const float f = fcw[c];
            g0 += f * W[c * 9 + kh * 3 + 0];
            g1 += f * W[c * 9 + kh * 3 + 1];
            g2 += f * W[c * 9 + kh * 3 + 2];
        }
        // width-sum of same-padded 3-wide conv: edge columns lose one tap
        const float h = (j == 0) ? (g0 + g1)
                      : (j == 8) ? (g1 + g2)
                                 : (g0 + g1 + g2);
        cw[tid] = h * (1.0f / 18.0f);
    } else if (tid == 54) {
        float c0 = 0.f;
        #pragma unroll
        for (int c = 0; c < 5; ++c) c0 += fcw[c] * (bl[c] + br[c]);
        cconst = 0.5f * c0 + fcb[0];
    }
    __syncthreads();

    const int blk = blockIdx.x;      // b*T + t
    const int b = blk >> 8;          // T = 256
    const int t = blk & 255;
    const int d0 = tid * 4;

    // Unshifted accumulators: A (w0 taps), B (w1 taps), E (w2 taps)
    float A0=0.f,A1=0.f,A2=0.f,A3=0.f;
    float B0=0.f,B1=0.f,B2=0.f,B3=0.f;
    float E0=0.f,E1=0.f,E2=0.f,E3=0.f;

    const float* fb = feat + (size_t)b * TT * DD + d0;

    #pragma unroll
    for (int s = 0; s < 18; ++s) {
        const int off = (s < 9) ? (s - 10) : (s - 7);
        const int tt = t + off;
        if (tt < 0 || tt >= TT) continue;   // time zero-pad (block-uniform)
        const float4 v = *reinterpret_cast<const float4*>(fb + (size_t)tt * DD);
        const float w0 = cw[s];
        const float w1 = cw[18 + s];
        const float w2 = cw[36 + s];
        A0 += w0 * v.x; A1 += w0 * v.y; A2 += w0 * v.z; A3 += w0 * v.w;
        B0 += w1 * v.x; B1 += w1 * v.y; B2 += w1 * v.z; B3 += w1 * v.w;
        E0 += w2 * v.x; E1 += w2 * v.y; E2 += w2 * v.z; E3 += w2 * v.w;
    }

    // d-shift via cross-lane exchange: out[d] = A[d-1] + B[d] + E[d+1]
    const int lane = tid & 63;
    const int wv   = tid >> 6;
    float Am1 = __shfl_up(A3, 1);     // A[d0-1] from thread tid-1
    float Ep1 = __shfl_down(E0, 1);   // E[d0+4] from thread tid+1
    if (lane == 63) edgeA[wv] = A3;
    if (lane == 0)  edgeE[wv] = E0;
    __syncthreads();
    if (lane == 0)  Am1 = (wv > 0) ? edgeA[wv - 1] : 0.0f;  // tid==0: d-pad → 0
    if (lane == 63) Ep1 = (wv < 3) ? edgeE[wv + 1] : 0.0f;  // tid==255: d-pad → 0

    const float Cst = cconst;
    float4 o;
    o.x = Cst + Am1 + B0 + E1;
    o.y = Cst + A0  + B1 + E2;
    o.z = Cst + A1  + B2 + E3;
    o.w = Cst + A2  + B3 + Ep1;
    *reinterpret_cast<float4*>(out + (size_t)blk * DD + d0) = o;
}

extern "C" void kernel_launch(void* const* d_in, const int* in_sizes, int n_in,
                              void* d_out, int out_size, void* d_ws, size_t ws_size,
                              hipStream_t stream) {
    const float* feat = (const float*)d_in[0];
    const float* wl   = (const float*)d_in[1];
    const float* bl   = (const float*)d_in[2];
    const float* wr   = (const float*)d_in[3];
    const float* br   = (const float*)d_in[4];
    const float* fcw  = (const float*)d_in[5];
    const float* fcb  = (const float*)d_in[6];
    float* out = (float*)d_out;

    dim3 grid(BB * TT);   // 1024 blocks, one per (b,t)
    dim3 block(256);      // 4 d's per thread
    sbl_stencil2_kernel<<<grid, block, 0, stream>>>(feat, wl, bl, wr, br, fcw, fcb, out);
}

// Round 3
// 13.000 us; speedup vs baseline: 1.4635x; 1.0473x over previous
//
#include <hip/hip_runtime.h>

#define BB 4
#define TT 256
#define DD 1024

// wq[kh][6]: {eL0, mL, eL8, eR0, mR, eR8} per kh, 1/18 folded in.
// kh=0 multiplies f[d-1], kh=1 f[d], kh=2 f[d+1] in out[d].

template <bool SAFE>
__device__ __forceinline__ void compute_taps(
    const float* __restrict__ fb, int t, const float (*wq)[6],
    float4& accA, float4& accB, float4& accE)
{
    float4 v[18];
    #pragma unroll
    for (int i = 0; i < 18; ++i) {
        const int off = (i < 9) ? (i - 10) : (i - 7);
        const int tt = t + off;
        if (SAFE || ((unsigned)tt < TT)) {
            v[i] = *reinterpret_cast<const float4*>(fb + (size_t)tt * DD);
        } else {
            v[i] = make_float4(0.f, 0.f, 0.f, 0.f);
        }
    }

    // shared 7-row window sums (middle columns j=1..7 of each side)
    float4 SL, SR;
    SL.x = ((v[1].x + v[2].x) + (v[3].x + v[4].x)) + ((v[5].x + v[6].x) + v[7].x);
    SL.y = ((v[1].y + v[2].y) + (v[3].y + v[4].y)) + ((v[5].y + v[6].y) + v[7].y);
    SL.z = ((v[1].z + v[2].z) + (v[3].z + v[4].z)) + ((v[5].z + v[6].z) + v[7].z);
    SL.w = ((v[1].w + v[2].w) + (v[3].w + v[4].w)) + ((v[5].w + v[6].w) + v[7].w);
    SR.x = ((v[10].x + v[11].x) + (v[12].x + v[13].x)) + ((v[14].x + v[15].x) + v[16].x);
    SR.y = ((v[10].y + v[11].y) + (v[12].y + v[13].y)) + ((v[14].y + v[15].y) + v[16].y);
    SR.z = ((v[10].z + v[11].z) + (v[12].z + v[13].z)) + ((v[14].z + v[15].z) + v[16].z);
    SR.w = ((v[10].w + v[11].w) + (v[12].w + v[13].w)) + ((v[14].w + v[15].w) + v[16].w);

    float4* accs[3] = { &accA, &accB, &accE };
    #pragma unroll
    for (int kh = 0; kh < 3; ++kh) {
        const float eL0 = wq[kh][0], mL = wq[kh][1], eL8 = wq[kh][2];
        const float eR0 = wq[kh][3], mR = wq[kh][4], eR8 = wq[kh][5];
        float4& a = *accs[kh];
        a.x = eL0*v[0].x + mL*SL.x + eL8*v[8].x + eR0*v[9].x + mR*SR.x + eR8*v[17].x;
        a.y = eL0*v[0].y + mL*SL.y + eL8*v[8].y + eR0*v[9].y + mR*SR.y + eR8*v[17].y;
        a.z = eL0*v[0].z + mL*SL.z + eL8*v[8].z + eR0*v[9].z + mR*SR.z + eR8*v[17].z;
        a.w = eL0*v[0].w + mL*SL.w + eL8*v[8].w + eR0*v[9].w + mR*SR.w + eR8*v[17].w;
    }
}

__global__ __launch_bounds__(256) void sbl_stencil3_kernel(
    const float* __restrict__ feat,
    const float* __restrict__ wl, const float* __restrict__ bl,
    const float* __restrict__ wr, const float* __restrict__ br,
    const float* __restrict__ fcw, const float* __restrict__ fcb,
    float* __restrict__ out)
{
    __shared__ float wq_s[3][6];
    __shared__ float cconst;
    __shared__ float edgeA[4], edgeE[4];

    const int tid = threadIdx.x;
    if (tid < 18) {
        const int kh = tid / 6;
        const int r = tid % 6;
        const int side = r / 3;     // 0 = left, 1 = right
        const int which = r % 3;    // 0 = edge0, 1 = mid, 2 = edge8
        const float* W = side ? wr : wl;
        float g0 = 0.f, g1 = 0.f, g2 = 0.f;
        #pragma unroll
        for (int c = 0; c < 5; ++c) {
            const float f = fcw[c];
            g0 += f * W[c * 9 + kh * 3 + 0];
            g1 += f * W[c * 9 + kh * 3 + 1];
            g2 += f * W[c * 9 + kh * 3 + 2];
        }
        const float h = (which == 0) ? (g0 + g1)
                      : (which == 1) ? (g0 + g1 + g2)
                                     : (g1 + g2);
        wq_s[kh][side * 3 + which] = h * (1.0f / 18.0f);
    } else if (tid == 18) {
        float c0 = 0.f;
        #pragma unroll
        for (int c = 0; c < 5; ++c) c0 += fcw[c] * (bl[c] + br[c]);
        cconst = 0.5f * c0 + fcb[0];
    }
    __syncthreads();

    const int blk = blockIdx.x;      // b*T + t
    const int b = blk >> 8;          // T = 256
    const int t = blk & 255;
    const int d0 = tid * 4;

    const float* fb = feat + (size_t)b * TT * DD + d0;

    float4 A, Bv, E;
    if (t >= 10 && t <= TT - 11) {
        compute_taps<true>(fb, t, wq_s, A, Bv, E);
    } else {
        compute_taps<false>(fb, t, wq_s, A, Bv, E);
    }

    // d-shift: out[d] = A[d-1] + B[d] + E[d+1] + const
    const int lane = tid & 63;
    const int wv   = tid >> 6;
    float Am1 = __shfl_up(A.w, 1);
    float Ep1 = __shfl_down(E.x, 1);
    if (lane == 63) edgeA[wv] = A.w;
    if (lane == 0)  edgeE[wv] = E.x;
    __syncthreads();
    if (lane == 0)  Am1 = (wv > 0) ? edgeA[wv - 1] : 0.0f;
    if (lane == 63) Ep1 = (wv < 3) ? edgeE[wv + 1] : 0.0f;

    const float C = cconst;
    float4 o;
    o.x = C + Am1 + Bv.x + E.y;
    o.y = C + A.x + Bv.y + E.z;
    o.z = C + A.y + Bv.z + E.w;
    o.w = C + A.z + Bv.w + Ep1;
    *reinterpret_cast<float4*>(out + (size_t)blk * DD + d0) = o;
}

extern "C" void kernel_launch(void* const* d_in, const int* in_sizes, int n_in,
                              void* d_out, int out_size, void* d_ws, size_t ws_size,
                              hipStream_t stream) {
    const float* feat = (const float*)d_in[0];
    const float* wl   = (const float*)d_in[1];
    const float* bl   = (const float*)d_in[2];
    const float* wr   = (const float*)d_in[3];
    const float* br   = (const float*)d_in[4];
    const float* fcw  = (const float*)d_in[5];
    const float* fcb  = (const float*)d_in[6];
    float* out = (float*)d_out;

    dim3 grid(BB * TT);   // 1024 blocks, one per (b,t)
    dim3 block(256);      // 4 d's per thread, float4
    sbl_stencil3_kernel<<<grid, block, 0, stream>>>(feat, wl, bl, wr, br, fcw, fcb, out);
}

// Round 4
// 10.866 us; speedup vs baseline: 1.7509x; 1.1964x over previous
//
#include <hip/hip_runtime.h>

#define BB 4
#define TT 256
#define DD 1024
#define TC 4   // t-values per thread; grid = BB * TT/TC = 256 blocks

__device__ __forceinline__ float4 f4zero() { return make_float4(0.f, 0.f, 0.f, 0.f); }
__device__ __forceinline__ float4 f4add(float4 a, float4 b) {
    return make_float4(a.x + b.x, a.y + b.y, a.z + b.z, a.w + b.w);
}
__device__ __forceinline__ float4 f4sub(float4 a, float4 b) {
    return make_float4(a.x - b.x, a.y - b.y, a.z - b.z, a.w - b.w);
}
__device__ __forceinline__ float4 f4fma(float w, float4 x, float4 acc) {
    return make_float4(fmaf(w, x.x, acc.x), fmaf(w, x.y, acc.y),
                       fmaf(w, x.z, acc.z), fmaf(w, x.w, acc.w));
}

__global__ __launch_bounds__(256, 1) void sbl_stencil4_kernel(
    const float* __restrict__ feat,
    const float* __restrict__ wl, const float* __restrict__ bl,
    const float* __restrict__ wr, const float* __restrict__ br,
    const float* __restrict__ fcw, const float* __restrict__ fcb,
    float* __restrict__ out)
{
    __shared__ float wq_s[3][6];   // {eL0, mL, eL8, eR0, mR, eR8} per kh, /18 folded
    __shared__ float cconst;
    __shared__ float eA[TC][4], eE[TC][4];

    const int tid = threadIdx.x;
    const int blk = blockIdx.x;
    const int b  = blk >> 6;          // TT/TC = 64 chunks per batch
    const int t0 = (blk & 63) << 2;
    const int d0 = tid * 4;
    const float* fb = feat + (size_t)b * TT * DD + d0;

    // ---- issue all 24 row loads first (overlaps weight-prep latency) ----
    float4 v[24];   // rows t0-10 .. t0+13, zero outside [0,TT)
    if (t0 >= 10 && t0 <= 242) {
        #pragma unroll
        for (int i = 0; i < 24; ++i)
            v[i] = *reinterpret_cast<const float4*>(fb + (size_t)(t0 + i - 10) * DD);
    } else {
        #pragma unroll
        for (int i = 0; i < 24; ++i) {
            const int row = t0 + i - 10;
            v[i] = ((unsigned)row < TT)
                 ? *reinterpret_cast<const float4*>(fb + (size_t)row * DD)
                 : f4zero();
        }
    }

    // ---- effective weights (identical algebra to R3, verified) ----
    if (tid < 18) {
        const int kh = tid / 6;
        const int r = tid % 6;
        const int side = r / 3;     // 0 = left, 1 = right
        const int which = r % 3;    // 0 = edge0, 1 = mid, 2 = edge8
        const float* W = side ? wr : wl;
        float g0 = 0.f, g1 = 0.f, g2 = 0.f;
        #pragma unroll
        for (int c = 0; c < 5; ++c) {
            const float f = fcw[c];
            g0 += f * W[c * 9 + kh * 3 + 0];
            g1 += f * W[c * 9 + kh * 3 + 1];
            g2 += f * W[c * 9 + kh * 3 + 2];
        }
        const float h = (which == 0) ? (g0 + g1)
                      : (which == 1) ? (g0 + g1 + g2)
                                     : (g1 + g2);
        wq_s[kh][side * 3 + which] = h * (1.0f / 18.0f);
    } else if (tid == 18) {
        float c0 = 0.f;
        #pragma unroll
        for (int c = 0; c < 5; ++c) c0 += fcw[c] * (bl[c] + br[c]);
        cconst = 0.5f * c0 + fcb[0];
    }
    __syncthreads();

    // ---- sliding 7-row window sums; taps for t = t0+j use v[j + off+10] ----
    // SL(j) = sum v[j+1 .. j+7]; SR(j) = sum v[j+13 .. j+19]
    float4 SL = f4add(f4add(f4add(v[1], v[2]), f4add(v[3], v[4])),
                      f4add(f4add(v[5], v[6]), v[7]));
    float4 SR = f4add(f4add(f4add(v[13], v[14]), f4add(v[15], v[16])),
                      f4add(f4add(v[17], v[18]), v[19]));

    float4 A[TC], Bv[TC], E[TC];
    #pragma unroll
    for (int j = 0; j < TC; ++j) {
        if (j > 0) {
            SL = f4add(f4sub(SL, v[j]), v[j + 7]);
            SR = f4add(f4sub(SR, v[j + 12]), v[j + 19]);
        }
        #pragma unroll
        for (int kh = 0; kh < 3; ++kh) {
            float4 a = f4zero();
            a = f4fma(wq_s[kh][0], v[j],      a);   // eL0 * f[t-10]
            a = f4fma(wq_s[kh][1], SL,        a);   // mL  * SL
            a = f4fma(wq_s[kh][2], v[j + 8],  a);   // eL8 * f[t-2]
            a = f4fma(wq_s[kh][3], v[j + 12], a);   // eR0 * f[t+2]
            a = f4fma(wq_s[kh][4], SR,        a);   // mR  * SR
            a = f4fma(wq_s[kh][5], v[j + 20], a);   // eR8 * f[t+10]
            if (kh == 0) A[j] = a; else if (kh == 1) Bv[j] = a; else E[j] = a;
        }
    }

    // ---- d-shift: out[d] = A[d-1] + B[d] + E[d+1] + const ----
    const int lane = tid & 63;
    const int wv   = tid >> 6;
    if (lane == 63) {
        #pragma unroll
        for (int j = 0; j < TC; ++j) eA[j][wv] = A[j].w;
    }
    if (lane == 0) {
        #pragma unroll
        for (int j = 0; j < TC; ++j) eE[j][wv] = E[j].x;
    }
    __syncthreads();

    const float C = cconst;
    float* ob = out + ((size_t)(b * TT + t0) * DD + d0);
    #pragma unroll
    for (int j = 0; j < TC; ++j) {
        float Am1 = __shfl_up(A[j].w, 1);
        float Ep1 = __shfl_down(E[j].x, 1);
        if (lane == 0)  Am1 = (wv > 0) ? eA[j][wv - 1] : 0.0f;
        if (lane == 63) Ep1 = (wv < 3) ? eE[j][wv + 1] : 0.0f;
        float4 o;
        o.x = C + Am1    + Bv[j].x + E[j].y;
        o.y = C + A[j].x + Bv[j].y + E[j].z;
        o.z = C + A[j].y + Bv[j].z + E[j].w;
        o.w = C + A[j].z + Bv[j].w + Ep1;
        *reinterpret_cast<float4*>(ob + (size_t)j * DD) = o;
    }
}

extern "C" void kernel_launch(void* const* d_in, const int* in_sizes, int n_in,
                              void* d_out, int out_size, void* d_ws, size_t ws_size,
                              hipStream_t stream) {
    const float* feat = (const float*)d_in[0];
    const float* wl   = (const float*)d_in[1];
    const float* bl   = (const float*)d_in[2];
    const float* wr   = (const float*)d_in[3];
    const float* br   = (const float*)d_in[4];
    const float* fcw  = (const float*)d_in[5];
    const float* fcb  = (const float*)d_in[6];
    float* out = (float*)d_out;

    dim3 grid(BB * (TT / TC));   // 256 blocks, one per (b, t-chunk)
    dim3 block(256);             // 4 d's per thread, TC t's per thread
    sbl_stencil4_kernel<<<grid, block, 0, stream>>>(feat, wl, bl, wr, br, fcw, fcb, out);
}